// Round 9
// baseline (193.805 us; speedup 1.0000x reference)
//
#include <hip/hip_runtime.h>

#define BATCH 32
#define KVLEN 2048
#define HDIM 1024
#define NHEAD 16
#define DHEAD 64
#define FFDIM 4096
#define LN_EPS 1e-5f
#define NCHUNK 64
#define ROWS_PER_BLOCK 32    // 4 waves * 8 rows
#define ROWS_PER_WAVE 8

// Non-temporal float4 load (emits global_load_dwordx4 nt): for streamed-once
// data (K/V cache, weight matrices) — evict-first, relieves cache-fill
// pressure. Reused data (q, x rows) stays on the normal path.
typedef float f32x4_t __attribute__((ext_vector_type(4)));
__device__ __forceinline__ float4 ntload4(const float* p) {
    f32x4_t v = __builtin_nontemporal_load((const f32x4_t*)p);
    return make_float4(v.x, v.y, v.z, v.w);
}

// ---------------------------------------------------------------------------
// GEMV over K=1024 chunk: out[b][j] = act(dot + bias + res).
// ROWS j-rows per wave; weight fragments persist in registers (nt-loaded,
// streamed once). 4-batch unroll: four independent 6-shuffle reduce chains
// interleave to hide the ~240cy chain latency (the GEMVs are latency-bound,
// not BW-bound: total weight traffic is only ~50 MB).
// ---------------------------------------------------------------------------
template<int ROWS, bool RELU, bool HAS_BIAS, bool HAS_RES, bool DUP_IKIV>
__global__ __launch_bounds__(256) void gemv_k1024(
    const float* __restrict__ in, int in_bstride, int in_coff,
    const float* __restrict__ W, int w_jstride, int w_coff,
    const float* __restrict__ bias,
    const float* __restrict__ res, int res_bstride,
    float* __restrict__ out, int out_bstride, int out_coff,
    float* __restrict__ out_extra,
    int nJ)
{
    const int wave = (int)((blockIdx.x * blockDim.x + threadIdx.x) >> 6);
    const int lane = (int)(threadIdx.x & 63);
    const int j0 = wave * ROWS;
    if (j0 >= nJ) return;
    const int c = (int)blockIdx.y;
    const float* inp = in + (size_t)c * in_coff;
    const float* Wp  = W  + (size_t)c * w_coff;
    float* outp      = out + (size_t)c * out_coff;

    float4 w[ROWS][4];
#pragma unroll
    for (int jj = 0; jj < ROWS; ++jj) {
        const float* wr = Wp + (size_t)(j0 + jj) * w_jstride;
#pragma unroll
        for (int i = 0; i < 4; ++i) w[jj][i] = ntload4(wr + (lane + i * 64) * 4);
    }

    for (int b = 0; b < BATCH; b += 4) {
        float4 xv[4][4];
#pragma unroll
        for (int u = 0; u < 4; ++u) {
            const float4* xr = (const float4*)(inp + (size_t)(b + u) * in_bstride);
#pragma unroll
            for (int i = 0; i < 4; ++i) xv[u][i] = xr[lane + i * 64];
        }
        float s[4][ROWS];
#pragma unroll
        for (int u = 0; u < 4; ++u)
#pragma unroll
            for (int jj = 0; jj < ROWS; ++jj) {
                float a = 0.f;
#pragma unroll
                for (int i = 0; i < 4; ++i)
                    a += w[jj][i].x * xv[u][i].x + w[jj][i].y * xv[u][i].y
                       + w[jj][i].z * xv[u][i].z + w[jj][i].w * xv[u][i].w;
                s[u][jj] = a;
            }
        float v[4];
#pragma unroll
        for (int u = 0; u < 4; ++u) {
            if (ROWS == 4) {
                const bool b0 = (lane & 1), b1 = (lane & 2);
                float a0 = b0 ? s[u][0] : s[u][1];
                float t0 = (b0 ? s[u][1] : s[u][0]) + __shfl_xor(a0, 1, 64);
                float a1 = b0 ? s[u][2] : s[u][3];
                float t1 = (b0 ? s[u][3] : s[u][2]) + __shfl_xor(a1, 1, 64);
                float a2 = b1 ? t0 : t1;
                float r  = (b1 ? t1 : t0) + __shfl_xor(a2, 2, 64);
                r += __shfl_xor(r, 4, 64);
                r += __shfl_xor(r, 8, 64);
                r += __shfl_xor(r, 16, 64);
                r += __shfl_xor(r, 32, 64);
                v[u] = r;
            } else if (ROWS == 2) {
                const bool b0 = (lane & 1);
                float a0 = b0 ? s[u][0] : s[u][1];
                float r  = (b0 ? s[u][1] : s[u][0]) + __shfl_xor(a0, 1, 64);
                r += __shfl_xor(r, 2, 64);
                r += __shfl_xor(r, 4, 64);
                r += __shfl_xor(r, 8, 64);
                r += __shfl_xor(r, 16, 64);
                r += __shfl_xor(r, 32, 64);
                v[u] = r;
            } else {  // ROWS == 1
                float r = s[u][0];
                r += __shfl_xor(r, 1, 64);
                r += __shfl_xor(r, 2, 64);
                r += __shfl_xor(r, 4, 64);
                r += __shfl_xor(r, 8, 64);
                r += __shfl_xor(r, 16, 64);
                r += __shfl_xor(r, 32, 64);
                v[u] = r;
            }
        }
#pragma unroll
        for (int u = 0; u < 4; ++u) {
            if (lane < ROWS) {
                const int j = j0 + lane;
                float o = v[u];
                if (HAS_BIAS) o += bias[j];
                if (HAS_RES)  o += res[(size_t)(b + u) * res_bstride + j];
                if (RELU)     o = fmaxf(o, 0.f);
                outp[(size_t)(b + u) * out_bstride + j] = o;
                if (DUP_IKIV && j >= 1024) {
                    const int base = (j >= 2048) ? 65536 : 32768;
                    out_extra[base + (b + u) * 1024 + (j & 1023)] = o;
                }
            }
        }
    }
}

// ---------------------------------------------------------------------------
// Attention pass 1: block = (b, chunk of 32 rows), 256 threads = 4 waves,
// 8 rows/wave in sub-batches of 4. Contiguous-pass layout: pass i, lane l
// covers dims i*256 + l*4 (every load = contiguous 1KB); head = 4i + (l>>4).
// LDS ~16.5 KB -> 8 blocks/CU = 32 waves/CU with 16 loads/wave in flight
// (16 KB/CU in flight, 2x round 8). PLAIN launch_bounds: no VGPR clamp.
// ---------------------------------------------------------------------------
__global__ __launch_bounds__(256) void attn_part(
    const float* __restrict__ qkv,       // [32][3072]
    const float* __restrict__ k_cache,   // [32][2048][1024]
    const float* __restrict__ v_cache,
    float* __restrict__ pacc,            // [32][64][1024]
    float* __restrict__ pm,              // [32][64][16]
    float* __restrict__ pl)              // [32][64][16]
{
    const int b = (int)(blockIdx.x >> 6);
    const int c = (int)(blockIdx.x & 63);
    const int tid = (int)threadIdx.x;
    const int w = tid >> 6;      // wave 0..3
    const int l = tid & 63;

    const float* qrow = qkv + (size_t)b * 3072 + l * 4;
    float4 q[4];
#pragma unroll
    for (int i = 0; i < 4; ++i) q[i] = *(const float4*)(qrow + i * 256);

    const size_t rowbase = ((size_t)b * KVLEN + c * ROWS_PER_BLOCK + w * ROWS_PER_WAVE) * HDIM + l * 4;
    const float* kb = k_cache + rowbase;
    const float* vb = v_cache + rowbase;

    float m[4], ls[4];
    float4 acc[4];
#pragma unroll
    for (int i = 0; i < 4; ++i) {
        m[i] = -1e30f; ls[i] = 0.f;
        acc[i] = make_float4(0.f, 0.f, 0.f, 0.f);
    }

#pragma unroll
    for (int sb = 0; sb < 2; ++sb) {
        float4 kf[4][4];
#pragma unroll
        for (int r = 0; r < 4; ++r)
#pragma unroll
            for (int i = 0; i < 4; ++i)
                kf[r][i] = ntload4(kb + (size_t)(sb * 4 + r) * HDIM + i * 256);
        float s[4][4];
#pragma unroll
        for (int r = 0; r < 4; ++r) {
#pragma unroll
            for (int i = 0; i < 4; ++i) {
                float d = kf[r][i].x * q[i].x + kf[r][i].y * q[i].y
                        + kf[r][i].z * q[i].z + kf[r][i].w * q[i].w;
                d += __shfl_xor(d, 1, 64);
                d += __shfl_xor(d, 2, 64);
                d += __shfl_xor(d, 4, 64);
                d += __shfl_xor(d, 8, 64);
                s[r][i] = d * 0.125f;
            }
        }
        float4 vf[4][4];
#pragma unroll
        for (int r = 0; r < 4; ++r)
#pragma unroll
            for (int i = 0; i < 4; ++i)
                vf[r][i] = ntload4(vb + (size_t)(sb * 4 + r) * HDIM + i * 256);
#pragma unroll
        for (int i = 0; i < 4; ++i) {
            float mn = fmaxf(fmaxf(s[0][i], s[1][i]), fmaxf(s[2][i], s[3][i]));
            mn = fmaxf(mn, m[i]);
            const float corr = __expf(m[i] - mn);
            const float p0 = __expf(s[0][i] - mn);
            const float p1 = __expf(s[1][i] - mn);
            const float p2 = __expf(s[2][i] - mn);
            const float p3 = __expf(s[3][i] - mn);
            ls[i] = ls[i] * corr + (p0 + p1) + (p2 + p3);
            m[i] = mn;
            acc[i].x = acc[i].x * corr + p0 * vf[0][i].x + p1 * vf[1][i].x + p2 * vf[2][i].x + p3 * vf[3][i].x;
            acc[i].y = acc[i].y * corr + p0 * vf[0][i].y + p1 * vf[1][i].y + p2 * vf[2][i].y + p3 * vf[3][i].y;
            acc[i].z = acc[i].z * corr + p0 * vf[0][i].z + p1 * vf[1][i].z + p2 * vf[2][i].z + p3 * vf[3][i].z;
            acc[i].w = acc[i].w * corr + p0 * vf[0][i].w + p1 * vf[1][i].w + p2 * vf[2][i].w + p3 * vf[3][i].w;
        }
    }

    // --- cross-wave combine in LDS (4 waves) ---
    __shared__ float sacc[4][1024];
    __shared__ float smm[4][16], sll[4][16];
#pragma unroll
    for (int i = 0; i < 4; ++i)
        *(float4*)&sacc[w][i * 256 + l * 4] = acc[i];
    if ((l & 15) == 0) {
        const int g = l >> 4;
#pragma unroll
        for (int i = 0; i < 4; ++i) { smm[w][i * 4 + g] = m[i]; sll[w][i * 4 + g] = ls[i]; }
    }
    __syncthreads();

#pragma unroll
    for (int half = 0; half < 4; ++half) {
        const int p = tid + half * 256;
        const int h = p >> 6;
        float M = -1e30f;
#pragma unroll
        for (int w2 = 0; w2 < 4; ++w2) M = fmaxf(M, smm[w2][h]);
        float L = 0.f, o = 0.f;
#pragma unroll
        for (int w2 = 0; w2 < 4; ++w2) {
            const float f = __expf(smm[w2][h] - M);
            L += sll[w2][h] * f;
            o += sacc[w2][p] * f;
        }
        pacc[((size_t)b * NCHUNK + c) * 1024 + p] = o;
        if ((p & 63) == 0) {
            pm[((size_t)b * NCHUNK + c) * 16 + h] = M;
            pl[((size_t)b * NCHUNK + c) * 16 + h] = L;
        }
    }
}

// ---------------------------------------------------------------------------
// Attention pass 2: merge 64 chunk partials + appended token (row 2048).
// ---------------------------------------------------------------------------
__global__ __launch_bounds__(1024) void attn_finish(
    const float* __restrict__ qkv,
    const float* __restrict__ pacc, const float* __restrict__ pm,
    const float* __restrict__ pl, float* __restrict__ attn_out)
{
    const int b = (int)blockIdx.x;
    const int p = (int)threadIdx.x;
    const int h = p >> 6;
    const float qa = qkv[(size_t)b * 3072 + p];
    const float ka = qkv[(size_t)b * 3072 + 1024 + p];
    const float va = qkv[(size_t)b * 3072 + 2048 + p];
    float d = qa * ka;
#pragma unroll
    for (int off = 1; off < 64; off <<= 1) d += __shfl_xor(d, off, 64);
    const float s = d * 0.125f;

    float M = s;
#pragma unroll 16
    for (int c = 0; c < NCHUNK; ++c)
        M = fmaxf(M, pm[((size_t)b * NCHUNK + c) * 16 + h]);
    const float pa = __expf(s - M);
    float L = pa, o = pa * va;
#pragma unroll 8
    for (int c = 0; c < NCHUNK; ++c) {
        const float f = __expf(pm[((size_t)b * NCHUNK + c) * 16 + h] - M);
        L += pl[((size_t)b * NCHUNK + c) * 16 + h] * f;
        o += pacc[((size_t)b * NCHUNK + c) * 1024 + p] * f;
    }
    attn_out[(size_t)b * HDIM + p] = o / L;
}

// ---------------------------------------------------------------------------
// Row LayerNorm: 1 block per batch row of 1024.
// ---------------------------------------------------------------------------
__global__ __launch_bounds__(256) void ln_kernel(const float* __restrict__ in,
    const float* __restrict__ w, const float* __restrict__ bv,
    float* __restrict__ out)
{
    const int b = (int)blockIdx.x, tid = (int)threadIdx.x;
    const float4 v = ((const float4*)(in + (size_t)b * HDIM))[tid];
    float sum = v.x + v.y + v.z + v.w;
    float sq  = v.x * v.x + v.y * v.y + v.z * v.z + v.w * v.w;
#pragma unroll
    for (int off = 1; off < 64; off <<= 1) {
        sum += __shfl_xor(sum, off, 64);
        sq  += __shfl_xor(sq,  off, 64);
    }
    __shared__ float s1[4], s2[4];
    const int wid = tid >> 6, lane = tid & 63;
    if (lane == 0) { s1[wid] = sum; s2[wid] = sq; }
    __syncthreads();
    sum = s1[0] + s1[1] + s1[2] + s1[3];
    sq  = s2[0] + s2[1] + s2[2] + s2[3];
    const float mu = sum * (1.f / HDIM);
    const float var = sq * (1.f / HDIM) - mu * mu;
    const float rstd = rsqrtf(var + LN_EPS);
    const float4 wv = ((const float4*)w)[tid];
    const float4 bb = ((const float4*)bv)[tid];
    float4 o;
    o.x = (v.x - mu) * rstd * wv.x + bb.x;
    o.y = (v.y - mu) * rstd * wv.y + bb.y;
    o.z = (v.z - mu) * rstd * wv.z + bb.z;
    o.w = (v.w - mu) * rstd * wv.w + bb.w;
    ((float4*)(out + (size_t)b * HDIM))[tid] = o;
}

// ---------------------------------------------------------------------------
// MLP2 finish: sum 4 split-K partials + bias + residual, then LayerNorm.
// ---------------------------------------------------------------------------
__global__ __launch_bounds__(256) void mlp2_finish(const float* __restrict__ part,
    const float* __restrict__ x1, const float* __restrict__ mbias,
    const float* __restrict__ w, const float* __restrict__ bv,
    float* __restrict__ out)
{
    const int b = (int)blockIdx.x, tid = (int)threadIdx.x;
    float4 v = make_float4(0.f, 0.f, 0.f, 0.f);
#pragma unroll
    for (int c = 0; c < 4; ++c) {
        const float4 p = ((const float4*)(part + (size_t)c * 32768 + (size_t)b * HDIM))[tid];
        v.x += p.x; v.y += p.y; v.z += p.z; v.w += p.w;
    }
    const float4 r  = ((const float4*)(x1 + (size_t)b * HDIM))[tid];
    const float4 mb = ((const float4*)mbias)[tid];
    v.x += r.x + mb.x; v.y += r.y + mb.y; v.z += r.z + mb.z; v.w += r.w + mb.w;

    float sum = v.x + v.y + v.z + v.w;
    float sq  = v.x * v.x + v.y * v.y + v.z * v.z + v.w * v.w;
#pragma unroll
    for (int off = 1; off < 64; off <<= 1) {
        sum += __shfl_xor(sum, off, 64);
        sq  += __shfl_xor(sq,  off, 64);
    }
    __shared__ float s1[4], s2[4];
    const int wid = tid >> 6, lane = tid & 63;
    if (lane == 0) { s1[wid] = sum; s2[wid] = sq; }
    __syncthreads();
    sum = s1[0] + s1[1] + s1[2] + s1[3];
    sq  = s2[0] + s2[1] + s2[2] + s2[3];
    const float mu = sum * (1.f / HDIM);
    const float var = sq * (1.f / HDIM) - mu * mu;
    const float rstd = rsqrtf(var + LN_EPS);
    const float4 wv = ((const float4*)w)[tid];
    const float4 bb = ((const float4*)bv)[tid];
    float4 o;
    o.x = (v.x - mu) * rstd * wv.x + bb.x;
    o.y = (v.y - mu) * rstd * wv.y + bb.y;
    o.z = (v.z - mu) * rstd * wv.z + bb.z;
    o.w = (v.w - mu) * rstd * wv.w + bb.w;
    ((float4*)(out + (size_t)b * HDIM))[tid] = o;
}

extern "C" void kernel_launch(void* const* d_in, const int* in_sizes, int n_in,
                              void* d_out, int out_size, void* d_ws, size_t ws_size,
                              hipStream_t stream) {
    const float* x     = (const float*)d_in[0];
    const float* kc    = (const float*)d_in[1];
    const float* vc    = (const float*)d_in[2];
    const float* qkvw  = (const float*)d_in[3];
    const float* qkvb  = (const float*)d_in[4];
    const float* outw  = (const float*)d_in[5];
    const float* outb  = (const float*)d_in[6];
    const float* nw1   = (const float*)d_in[7];
    const float* nb1   = (const float*)d_in[8];
    const float* nw2   = (const float*)d_in[9];
    const float* nb2   = (const float*)d_in[10];
    const float* mw1   = (const float*)d_in[11];
    const float* mb1   = (const float*)d_in[12];
    const float* mw2   = (const float*)d_in[13];
    const float* mb2   = (const float*)d_in[14];
    float* out = (float*)d_out;

    float* ws   = (float*)d_ws;
    float* qkv  = ws;              // [32][3072]           = 98304
    float* pacc = ws + 98304;      // [32][64][1024]       = 2097152
    float* pmb  = ws + 2195456;    // [32][64][16]         = 32768
    float* plb  = ws + 2228224;    // [32][64][16]         = 32768
    float* attn = ws + 2260992;    // [32][1024]
    float* y1   = ws + 2293760;    // [32][1024]
    float* x1   = ws + 2326528;    // [32][1024]
    // pacc region is dead after attn_finish -> reuse for MLP buffers
    float* hbuf = pacc;            // [32][4096]           = 131072
    float* part = pacc + 131072;   // [4][32][1024]        = 131072

    // 1) fused QKV projection: ROWS=2 -> 1536 waves = 384 blocks
    gemv_k1024<2, false, true, false, true><<<dim3(384, 1), 256, 0, stream>>>(
        x, HDIM, 0, qkvw, HDIM, 0, qkvb, nullptr, 0, qkv, 3 * HDIM, 0, out, 3 * HDIM);

    // 2) attention pass 1: chunk partials (2048 blocks = 8/CU, nt streaming)
    attn_part<<<BATCH * NCHUNK, 256, 0, stream>>>(qkv, kc, vc, pacc, pmb, plb);

    // 3) attention pass 2: merge chunks + appended token
    attn_finish<<<BATCH, 1024, 0, stream>>>(qkv, pacc, pmb, plb, attn);

    // 4) output projection + residual: ROWS=1 -> 1024 waves = 256 blocks
    gemv_k1024<1, false, true, true, false><<<dim3(256, 1), 256, 0, stream>>>(
        attn, HDIM, 0, outw, HDIM, 0, outb, x, HDIM, y1, HDIM, 0, nullptr, HDIM);

    // 5) LayerNorm 1
    ln_kernel<<<BATCH, 256, 0, stream>>>(y1, nw1, nb1, x1);

    // 6) MLP up + ReLU: ROWS=2 -> 2048 waves = 512 blocks
    gemv_k1024<2, true, true, false, false><<<dim3(512, 1), 256, 0, stream>>>(
        x1, HDIM, 0, mw1, HDIM, 0, mb1, nullptr, 0, hbuf, FFDIM, 0, nullptr, FFDIM);

    // 7) MLP down: ROWS=1, split-K 4 -> (256, 4) = 1024 blocks
    gemv_k1024<1, false, false, false, false><<<dim3(256, 4), 256, 0, stream>>>(
        hbuf, FFDIM, HDIM, mw2, FFDIM, HDIM, nullptr, nullptr, 0,
        part, HDIM, BATCH * HDIM, nullptr, HDIM);

    // 8) reduce partials + bias + residual + LayerNorm 2 -> x output
    mlp2_finish<<<BATCH, 256, 0, stream>>>(part, x1, mb2, nw2, nb2, out);
}

// Round 10
// 171.352 us; speedup vs baseline: 1.1310x; 1.1310x over previous
//
#include <hip/hip_runtime.h>

#define BATCH 32
#define KVLEN 2048
#define HDIM 1024
#define NHEAD 16
#define DHEAD 64
#define FFDIM 4096
#define LN_EPS 1e-5f
#define NCHUNK 32
#define ROWS_PER_BLOCK 64    // 8 waves * 8 rows
#define ROWS_PER_WAVE 8

// Non-temporal float4 load (emits global_load_dwordx4 nt): for streamed-once
// data (K/V cache, weight matrices) — evict-first, relieves cache-fill
// pressure. Reused data (q, x rows) stays on the normal path.
typedef float f32x4_t __attribute__((ext_vector_type(4)));
__device__ __forceinline__ float4 ntload4(const float* p) {
    f32x4_t v = __builtin_nontemporal_load((const f32x4_t*)p);
    return make_float4(v.x, v.y, v.z, v.w);
}

// ---------------------------------------------------------------------------
// GEMV over K=1024 chunk: out[b][j] = act(dot + bias + res).
// ROWS j-rows per wave; weight fragments persist in registers (nt-loaded,
// streamed once). 4-batch unroll: four independent 6-shuffle reduce chains
// interleave to hide the ~240cy chain latency (the GEMVs are latency-bound,
// not BW-bound: total weight traffic is only ~50 MB).
// ---------------------------------------------------------------------------
template<int ROWS, bool RELU, bool HAS_BIAS, bool HAS_RES, bool DUP_IKIV>
__global__ __launch_bounds__(256) void gemv_k1024(
    const float* __restrict__ in, int in_bstride, int in_coff,
    const float* __restrict__ W, int w_jstride, int w_coff,
    const float* __restrict__ bias,
    const float* __restrict__ res, int res_bstride,
    float* __restrict__ out, int out_bstride, int out_coff,
    float* __restrict__ out_extra,
    int nJ)
{
    const int wave = (int)((blockIdx.x * blockDim.x + threadIdx.x) >> 6);
    const int lane = (int)(threadIdx.x & 63);
    const int j0 = wave * ROWS;
    if (j0 >= nJ) return;
    const int c = (int)blockIdx.y;
    const float* inp = in + (size_t)c * in_coff;
    const float* Wp  = W  + (size_t)c * w_coff;
    float* outp      = out + (size_t)c * out_coff;

    float4 w[ROWS][4];
#pragma unroll
    for (int jj = 0; jj < ROWS; ++jj) {
        const float* wr = Wp + (size_t)(j0 + jj) * w_jstride;
#pragma unroll
        for (int i = 0; i < 4; ++i) w[jj][i] = ntload4(wr + (lane + i * 64) * 4);
    }

    for (int b = 0; b < BATCH; b += 4) {
        float4 xv[4][4];
#pragma unroll
        for (int u = 0; u < 4; ++u) {
            const float4* xr = (const float4*)(inp + (size_t)(b + u) * in_bstride);
#pragma unroll
            for (int i = 0; i < 4; ++i) xv[u][i] = xr[lane + i * 64];
        }
        float s[4][ROWS];
#pragma unroll
        for (int u = 0; u < 4; ++u)
#pragma unroll
            for (int jj = 0; jj < ROWS; ++jj) {
                float a = 0.f;
#pragma unroll
                for (int i = 0; i < 4; ++i)
                    a += w[jj][i].x * xv[u][i].x + w[jj][i].y * xv[u][i].y
                       + w[jj][i].z * xv[u][i].z + w[jj][i].w * xv[u][i].w;
                s[u][jj] = a;
            }
        float v[4];
#pragma unroll
        for (int u = 0; u < 4; ++u) {
            if (ROWS == 4) {
                const bool b0 = (lane & 1), b1 = (lane & 2);
                float a0 = b0 ? s[u][0] : s[u][1];
                float t0 = (b0 ? s[u][1] : s[u][0]) + __shfl_xor(a0, 1, 64);
                float a1 = b0 ? s[u][2] : s[u][3];
                float t1 = (b0 ? s[u][3] : s[u][2]) + __shfl_xor(a1, 1, 64);
                float a2 = b1 ? t0 : t1;
                float r  = (b1 ? t1 : t0) + __shfl_xor(a2, 2, 64);
                r += __shfl_xor(r, 4, 64);
                r += __shfl_xor(r, 8, 64);
                r += __shfl_xor(r, 16, 64);
                r += __shfl_xor(r, 32, 64);
                v[u] = r;
            } else if (ROWS == 2) {
                const bool b0 = (lane & 1);
                float a0 = b0 ? s[u][0] : s[u][1];
                float r  = (b0 ? s[u][1] : s[u][0]) + __shfl_xor(a0, 1, 64);
                r += __shfl_xor(r, 2, 64);
                r += __shfl_xor(r, 4, 64);
                r += __shfl_xor(r, 8, 64);
                r += __shfl_xor(r, 16, 64);
                r += __shfl_xor(r, 32, 64);
                v[u] = r;
            } else {  // ROWS == 1
                float r = s[u][0];
                r += __shfl_xor(r, 1, 64);
                r += __shfl_xor(r, 2, 64);
                r += __shfl_xor(r, 4, 64);
                r += __shfl_xor(r, 8, 64);
                r += __shfl_xor(r, 16, 64);
                r += __shfl_xor(r, 32, 64);
                v[u] = r;
            }
        }
#pragma unroll
        for (int u = 0; u < 4; ++u) {
            if (lane < ROWS) {
                const int j = j0 + lane;
                float o = v[u];
                if (HAS_BIAS) o += bias[j];
                if (HAS_RES)  o += res[(size_t)(b + u) * res_bstride + j];
                if (RELU)     o = fmaxf(o, 0.f);
                outp[(size_t)(b + u) * out_bstride + j] = o;
                if (DUP_IKIV && j >= 1024) {
                    const int base = (j >= 2048) ? 65536 : 32768;
                    out_extra[base + (b + u) * 1024 + (j & 1023)] = o;
                }
            }
        }
    }
}

// ---------------------------------------------------------------------------
// Attention pass 1 (round-8 config — best measured): block = (b, chunk of 64
// rows), 512 threads = 8 waves, 8 rows/wave in sub-batches of 4. Contiguous-
// pass layout: pass i, lane l covers dims i*256 + l*4 (every load = contiguous
// 1KB); head = 4i + (l>>4). 1024 blocks = 4 blocks/CU. PLAIN launch_bounds:
// a (512,8) bound clamps VGPR to 32 and spills (round-6 lesson). Pushing to
// 8 blocks/CU (round 9) gave no gain: ~4.2 TB/s nt-read is the plateau.
// ---------------------------------------------------------------------------
__global__ __launch_bounds__(512) void attn_part(
    const float* __restrict__ qkv,       // [32][3072]
    const float* __restrict__ k_cache,   // [32][2048][1024]
    const float* __restrict__ v_cache,
    float* __restrict__ pacc,            // [32][32][1024]
    float* __restrict__ pm,              // [32][32][16]
    float* __restrict__ pl)              // [32][32][16]
{
    const int b = (int)(blockIdx.x >> 5);
    const int c = (int)(blockIdx.x & 31);
    const int tid = (int)threadIdx.x;
    const int w = tid >> 6;      // wave 0..7
    const int l = tid & 63;

    const float* qrow = qkv + (size_t)b * 3072 + l * 4;
    float4 q[4];
#pragma unroll
    for (int i = 0; i < 4; ++i) q[i] = *(const float4*)(qrow + i * 256);

    const size_t rowbase = ((size_t)b * KVLEN + c * ROWS_PER_BLOCK + w * ROWS_PER_WAVE) * HDIM + l * 4;
    const float* kb = k_cache + rowbase;
    const float* vb = v_cache + rowbase;

    float m[4], ls[4];
    float4 acc[4];
#pragma unroll
    for (int i = 0; i < 4; ++i) {
        m[i] = -1e30f; ls[i] = 0.f;
        acc[i] = make_float4(0.f, 0.f, 0.f, 0.f);
    }

#pragma unroll
    for (int sb = 0; sb < 2; ++sb) {
        float4 kf[4][4];
#pragma unroll
        for (int r = 0; r < 4; ++r)
#pragma unroll
            for (int i = 0; i < 4; ++i)
                kf[r][i] = ntload4(kb + (size_t)(sb * 4 + r) * HDIM + i * 256);
        float s[4][4];
#pragma unroll
        for (int r = 0; r < 4; ++r) {
#pragma unroll
            for (int i = 0; i < 4; ++i) {
                float d = kf[r][i].x * q[i].x + kf[r][i].y * q[i].y
                        + kf[r][i].z * q[i].z + kf[r][i].w * q[i].w;
                d += __shfl_xor(d, 1, 64);
                d += __shfl_xor(d, 2, 64);
                d += __shfl_xor(d, 4, 64);
                d += __shfl_xor(d, 8, 64);
                s[r][i] = d * 0.125f;
            }
        }
        float4 vf[4][4];
#pragma unroll
        for (int r = 0; r < 4; ++r)
#pragma unroll
            for (int i = 0; i < 4; ++i)
                vf[r][i] = ntload4(vb + (size_t)(sb * 4 + r) * HDIM + i * 256);
#pragma unroll
        for (int i = 0; i < 4; ++i) {
            float mn = fmaxf(fmaxf(s[0][i], s[1][i]), fmaxf(s[2][i], s[3][i]));
            mn = fmaxf(mn, m[i]);
            const float corr = __expf(m[i] - mn);
            const float p0 = __expf(s[0][i] - mn);
            const float p1 = __expf(s[1][i] - mn);
            const float p2 = __expf(s[2][i] - mn);
            const float p3 = __expf(s[3][i] - mn);
            ls[i] = ls[i] * corr + (p0 + p1) + (p2 + p3);
            m[i] = mn;
            acc[i].x = acc[i].x * corr + p0 * vf[0][i].x + p1 * vf[1][i].x + p2 * vf[2][i].x + p3 * vf[3][i].x;
            acc[i].y = acc[i].y * corr + p0 * vf[0][i].y + p1 * vf[1][i].y + p2 * vf[2][i].y + p3 * vf[3][i].y;
            acc[i].z = acc[i].z * corr + p0 * vf[0][i].z + p1 * vf[1][i].z + p2 * vf[2][i].z + p3 * vf[3][i].z;
            acc[i].w = acc[i].w * corr + p0 * vf[0][i].w + p1 * vf[1][i].w + p2 * vf[2][i].w + p3 * vf[3][i].w;
        }
    }

    __shared__ float sacc[8][1024];
    __shared__ float smm[8][16], sll[8][16];
#pragma unroll
    for (int i = 0; i < 4; ++i)
        *(float4*)&sacc[w][i * 256 + l * 4] = acc[i];
    if ((l & 15) == 0) {
        const int g = l >> 4;
#pragma unroll
        for (int i = 0; i < 4; ++i) { smm[w][i * 4 + g] = m[i]; sll[w][i * 4 + g] = ls[i]; }
    }
    __syncthreads();

#pragma unroll
    for (int half = 0; half < 2; ++half) {
        const int p = tid + half * 512;
        const int h = p >> 6;
        float M = -1e30f;
#pragma unroll
        for (int w2 = 0; w2 < 8; ++w2) M = fmaxf(M, smm[w2][h]);
        float L = 0.f, o = 0.f;
#pragma unroll
        for (int w2 = 0; w2 < 8; ++w2) {
            const float f = __expf(smm[w2][h] - M);
            L += sll[w2][h] * f;
            o += sacc[w2][p] * f;
        }
        pacc[((size_t)b * NCHUNK + c) * 1024 + p] = o;
        if ((p & 63) == 0) {
            pm[((size_t)b * NCHUNK + c) * 16 + h] = M;
            pl[((size_t)b * NCHUNK + c) * 16 + h] = L;
        }
    }
}

// ---------------------------------------------------------------------------
// Attention pass 2: merge 32 chunk partials + appended token (row 2048).
// ---------------------------------------------------------------------------
__global__ __launch_bounds__(1024) void attn_finish(
    const float* __restrict__ qkv,
    const float* __restrict__ pacc, const float* __restrict__ pm,
    const float* __restrict__ pl, float* __restrict__ attn_out)
{
    const int b = (int)blockIdx.x;
    const int p = (int)threadIdx.x;
    const int h = p >> 6;
    const float qa = qkv[(size_t)b * 3072 + p];
    const float ka = qkv[(size_t)b * 3072 + 1024 + p];
    const float va = qkv[(size_t)b * 3072 + 2048 + p];
    float d = qa * ka;
#pragma unroll
    for (int off = 1; off < 64; off <<= 1) d += __shfl_xor(d, off, 64);
    const float s = d * 0.125f;

    float M = s;
#pragma unroll
    for (int c = 0; c < NCHUNK; ++c)
        M = fmaxf(M, pm[((size_t)b * NCHUNK + c) * 16 + h]);
    const float pa = __expf(s - M);
    float L = pa, o = pa * va;
#pragma unroll 8
    for (int c = 0; c < NCHUNK; ++c) {
        const float f = __expf(pm[((size_t)b * NCHUNK + c) * 16 + h] - M);
        L += pl[((size_t)b * NCHUNK + c) * 16 + h] * f;
        o += pacc[((size_t)b * NCHUNK + c) * 1024 + p] * f;
    }
    attn_out[(size_t)b * HDIM + p] = o / L;
}

// ---------------------------------------------------------------------------
// Row LayerNorm: 1 block per batch row of 1024.
// ---------------------------------------------------------------------------
__global__ __launch_bounds__(256) void ln_kernel(const float* __restrict__ in,
    const float* __restrict__ w, const float* __restrict__ bv,
    float* __restrict__ out)
{
    const int b = (int)blockIdx.x, tid = (int)threadIdx.x;
    const float4 v = ((const float4*)(in + (size_t)b * HDIM))[tid];
    float sum = v.x + v.y + v.z + v.w;
    float sq  = v.x * v.x + v.y * v.y + v.z * v.z + v.w * v.w;
#pragma unroll
    for (int off = 1; off < 64; off <<= 1) {
        sum += __shfl_xor(sum, off, 64);
        sq  += __shfl_xor(sq,  off, 64);
    }
    __shared__ float s1[4], s2[4];
    const int wid = tid >> 6, lane = tid & 63;
    if (lane == 0) { s1[wid] = sum; s2[wid] = sq; }
    __syncthreads();
    sum = s1[0] + s1[1] + s1[2] + s1[3];
    sq  = s2[0] + s2[1] + s2[2] + s2[3];
    const float mu = sum * (1.f / HDIM);
    const float var = sq * (1.f / HDIM) - mu * mu;
    const float rstd = rsqrtf(var + LN_EPS);
    const float4 wv = ((const float4*)w)[tid];
    const float4 bb = ((const float4*)bv)[tid];
    float4 o;
    o.x = (v.x - mu) * rstd * wv.x + bb.x;
    o.y = (v.y - mu) * rstd * wv.y + bb.y;
    o.z = (v.z - mu) * rstd * wv.z + bb.z;
    o.w = (v.w - mu) * rstd * wv.w + bb.w;
    ((float4*)(out + (size_t)b * HDIM))[tid] = o;
}

// ---------------------------------------------------------------------------
// MLP2 finish: sum 4 split-K partials + bias + residual, then LayerNorm.
// ---------------------------------------------------------------------------
__global__ __launch_bounds__(256) void mlp2_finish(const float* __restrict__ part,
    const float* __restrict__ x1, const float* __restrict__ mbias,
    const float* __restrict__ w, const float* __restrict__ bv,
    float* __restrict__ out)
{
    const int b = (int)blockIdx.x, tid = (int)threadIdx.x;
    float4 v = make_float4(0.f, 0.f, 0.f, 0.f);
#pragma unroll
    for (int c = 0; c < 4; ++c) {
        const float4 p = ((const float4*)(part + (size_t)c * 32768 + (size_t)b * HDIM))[tid];
        v.x += p.x; v.y += p.y; v.z += p.z; v.w += p.w;
    }
    const float4 r  = ((const float4*)(x1 + (size_t)b * HDIM))[tid];
    const float4 mb = ((const float4*)mbias)[tid];
    v.x += r.x + mb.x; v.y += r.y + mb.y; v.z += r.z + mb.z; v.w += r.w + mb.w;

    float sum = v.x + v.y + v.z + v.w;
    float sq  = v.x * v.x + v.y * v.y + v.z * v.z + v.w * v.w;
#pragma unroll
    for (int off = 1; off < 64; off <<= 1) {
        sum += __shfl_xor(sum, off, 64);
        sq  += __shfl_xor(sq,  off, 64);
    }
    __shared__ float s1[4], s2[4];
    const int wid = tid >> 6, lane = tid & 63;
    if (lane == 0) { s1[wid] = sum; s2[wid] = sq; }
    __syncthreads();
    sum = s1[0] + s1[1] + s1[2] + s1[3];
    sq  = s2[0] + s2[1] + s2[2] + s2[3];
    const float mu = sum * (1.f / HDIM);
    const float var = sq * (1.f / HDIM) - mu * mu;
    const float rstd = rsqrtf(var + LN_EPS);
    const float4 wv = ((const float4*)w)[tid];
    const float4 bb = ((const float4*)bv)[tid];
    float4 o;
    o.x = (v.x - mu) * rstd * wv.x + bb.x;
    o.y = (v.y - mu) * rstd * wv.y + bb.y;
    o.z = (v.z - mu) * rstd * wv.z + bb.z;
    o.w = (v.w - mu) * rstd * wv.w + bb.w;
    ((float4*)(out + (size_t)b * HDIM))[tid] = o;
}

extern "C" void kernel_launch(void* const* d_in, const int* in_sizes, int n_in,
                              void* d_out, int out_size, void* d_ws, size_t ws_size,
                              hipStream_t stream) {
    const float* x     = (const float*)d_in[0];
    const float* kc    = (const float*)d_in[1];
    const float* vc    = (const float*)d_in[2];
    const float* qkvw  = (const float*)d_in[3];
    const float* qkvb  = (const float*)d_in[4];
    const float* outw  = (const float*)d_in[5];
    const float* outb  = (const float*)d_in[6];
    const float* nw1   = (const float*)d_in[7];
    const float* nb1   = (const float*)d_in[8];
    const float* nw2   = (const float*)d_in[9];
    const float* nb2   = (const float*)d_in[10];
    const float* mw1   = (const float*)d_in[11];
    const float* mb1   = (const float*)d_in[12];
    const float* mw2   = (const float*)d_in[13];
    const float* mb2   = (const float*)d_in[14];
    float* out = (float*)d_out;

    float* ws   = (float*)d_ws;
    float* qkv  = ws;              // [32][3072]           = 98304
    float* pacc = ws + 98304;      // [32][32][1024]       = 1048576
    float* pmb  = ws + 1146880;    // [32][32][16]         = 16384
    float* plb  = ws + 1163264;    // [32][32][16]         = 16384
    float* attn = ws + 1179648;    // [32][1024]
    float* y1   = ws + 1212416;    // [32][1024]
    float* x1   = ws + 1245184;    // [32][1024]
    // pacc region is dead after attn_finish -> reuse for MLP buffers
    float* hbuf = pacc;            // [32][4096]           = 131072
    float* part = pacc + 131072;   // [4][32][1024]        = 131072

    // 1) fused QKV projection: ROWS=2 -> 1536 waves = 384 blocks
    gemv_k1024<2, false, true, false, true><<<dim3(384, 1), 256, 0, stream>>>(
        x, HDIM, 0, qkvw, HDIM, 0, qkvb, nullptr, 0, qkv, 3 * HDIM, 0, out, 3 * HDIM);

    // 2) attention pass 1: chunk partials (1024 blocks = 4/CU, nt streaming)
    attn_part<<<BATCH * NCHUNK, 512, 0, stream>>>(qkv, kc, vc, pacc, pmb, plb);

    // 3) attention pass 2: merge chunks + appended token
    attn_finish<<<BATCH, 1024, 0, stream>>>(qkv, pacc, pmb, plb, attn);

    // 4) output projection + residual: ROWS=1 -> 1024 waves = 256 blocks
    gemv_k1024<1, false, true, true, false><<<dim3(256, 1), 256, 0, stream>>>(
        attn, HDIM, 0, outw, HDIM, 0, outb, x, HDIM, y1, HDIM, 0, nullptr, HDIM);

    // 5) LayerNorm 1
    ln_kernel<<<BATCH, 256, 0, stream>>>(y1, nw1, nb1, x1);

    // 6) MLP up + ReLU: ROWS=2 -> 2048 waves = 512 blocks
    gemv_k1024<2, true, true, false, false><<<dim3(512, 1), 256, 0, stream>>>(
        x1, HDIM, 0, mw1, HDIM, 0, mb1, nullptr, 0, hbuf, FFDIM, 0, nullptr, FFDIM);

    // 7) MLP down: ROWS=1, split-K 4 -> (256, 4) = 1024 blocks
    gemv_k1024<1, false, false, false, false><<<dim3(256, 4), 256, 0, stream>>>(
        hbuf, FFDIM, HDIM, mw2, FFDIM, HDIM, nullptr, nullptr, 0,
        part, HDIM, BATCH * HDIM, nullptr, HDIM);

    // 8) reduce partials + bias + residual + LayerNorm 2 -> x output
    mlp2_finish<<<BATCH, 256, 0, stream>>>(part, x1, mb2, nw2, nb2, out);
}

// Round 11
// 167.615 us; speedup vs baseline: 1.1563x; 1.0223x over previous
//
#include <hip/hip_runtime.h>

#define BATCH 32
#define KVLEN 2048
#define HDIM 1024
#define NHEAD 16
#define DHEAD 64
#define FFDIM 4096
#define LN_EPS 1e-5f
#define NCHUNK 32
#define ROWS_PER_BLOCK 64    // 8 waves * 8 rows
#define ROWS_PER_WAVE 8

// Non-temporal float4 load (emits global_load_dwordx4 nt): for streamed-once
// data (K/V cache, weight matrices) — evict-first, relieves cache-fill
// pressure. Reused data (q, x rows) stays on the normal path.
typedef float f32x4_t __attribute__((ext_vector_type(4)));
__device__ __forceinline__ float4 ntload4(const float* p) {
    f32x4_t v = __builtin_nontemporal_load((const f32x4_t*)p);
    return make_float4(v.x, v.y, v.z, v.w);
}

// ---------------------------------------------------------------------------
// GEMV over K=1024 chunk: out[b][j] = act(dot + bias + res).
// ROWS j-rows per wave; weight fragments persist in registers (nt-loaded,
// streamed once). 8-batch unroll: eight independent 6-shuffle reduce chains
// interleave to hide the ~240cy chain latency (the GEMVs are latency-bound,
// not BW-bound; depth 2->4 was worth -19us, this doubles ILP again).
// ---------------------------------------------------------------------------
template<int ROWS, bool RELU, bool HAS_BIAS, bool HAS_RES, bool DUP_IKIV>
__global__ __launch_bounds__(256) void gemv_k1024(
    const float* __restrict__ in, int in_bstride, int in_coff,
    const float* __restrict__ W, int w_jstride, int w_coff,
    const float* __restrict__ bias,
    const float* __restrict__ res, int res_bstride,
    float* __restrict__ out, int out_bstride, int out_coff,
    float* __restrict__ out_extra,
    int nJ)
{
    const int wave = (int)((blockIdx.x * blockDim.x + threadIdx.x) >> 6);
    const int lane = (int)(threadIdx.x & 63);
    const int j0 = wave * ROWS;
    if (j0 >= nJ) return;
    const int c = (int)blockIdx.y;
    const float* inp = in + (size_t)c * in_coff;
    const float* Wp  = W  + (size_t)c * w_coff;
    float* outp      = out + (size_t)c * out_coff;

    float4 w[ROWS][4];
#pragma unroll
    for (int jj = 0; jj < ROWS; ++jj) {
        const float* wr = Wp + (size_t)(j0 + jj) * w_jstride;
#pragma unroll
        for (int i = 0; i < 4; ++i) w[jj][i] = ntload4(wr + (lane + i * 64) * 4);
    }

    for (int b = 0; b < BATCH; b += 8) {
        float4 xv[8][4];
#pragma unroll
        for (int u = 0; u < 8; ++u) {
            const float4* xr = (const float4*)(inp + (size_t)(b + u) * in_bstride);
#pragma unroll
            for (int i = 0; i < 4; ++i) xv[u][i] = xr[lane + i * 64];
        }
        float s[8][ROWS];
#pragma unroll
        for (int u = 0; u < 8; ++u)
#pragma unroll
            for (int jj = 0; jj < ROWS; ++jj) {
                float a = 0.f;
#pragma unroll
                for (int i = 0; i < 4; ++i)
                    a += w[jj][i].x * xv[u][i].x + w[jj][i].y * xv[u][i].y
                       + w[jj][i].z * xv[u][i].z + w[jj][i].w * xv[u][i].w;
                s[u][jj] = a;
            }
        float v[8];
#pragma unroll
        for (int u = 0; u < 8; ++u) {
            if (ROWS == 4) {
                const bool b0 = (lane & 1), b1 = (lane & 2);
                float a0 = b0 ? s[u][0] : s[u][1];
                float t0 = (b0 ? s[u][1] : s[u][0]) + __shfl_xor(a0, 1, 64);
                float a1 = b0 ? s[u][2] : s[u][3];
                float t1 = (b0 ? s[u][3] : s[u][2]) + __shfl_xor(a1, 1, 64);
                float a2 = b1 ? t0 : t1;
                float r  = (b1 ? t1 : t0) + __shfl_xor(a2, 2, 64);
                r += __shfl_xor(r, 4, 64);
                r += __shfl_xor(r, 8, 64);
                r += __shfl_xor(r, 16, 64);
                r += __shfl_xor(r, 32, 64);
                v[u] = r;
            } else if (ROWS == 2) {
                const bool b0 = (lane & 1);
                float a0 = b0 ? s[u][0] : s[u][1];
                float r  = (b0 ? s[u][1] : s[u][0]) + __shfl_xor(a0, 1, 64);
                r += __shfl_xor(r, 2, 64);
                r += __shfl_xor(r, 4, 64);
                r += __shfl_xor(r, 8, 64);
                r += __shfl_xor(r, 16, 64);
                r += __shfl_xor(r, 32, 64);
                v[u] = r;
            } else {  // ROWS == 1
                float r = s[u][0];
                r += __shfl_xor(r, 1, 64);
                r += __shfl_xor(r, 2, 64);
                r += __shfl_xor(r, 4, 64);
                r += __shfl_xor(r, 8, 64);
                r += __shfl_xor(r, 16, 64);
                r += __shfl_xor(r, 32, 64);
                v[u] = r;
            }
        }
#pragma unroll
        for (int u = 0; u < 8; ++u) {
            if (lane < ROWS) {
                const int j = j0 + lane;
                float o = v[u];
                if (HAS_BIAS) o += bias[j];
                if (HAS_RES)  o += res[(size_t)(b + u) * res_bstride + j];
                if (RELU)     o = fmaxf(o, 0.f);
                outp[(size_t)(b + u) * out_bstride + j] = o;
                if (DUP_IKIV && j >= 1024) {
                    const int base = (j >= 2048) ? 65536 : 32768;
                    out_extra[base + (b + u) * 1024 + (j & 1023)] = o;
                }
            }
        }
    }
}

// ---------------------------------------------------------------------------
// Attention pass 1 (round-8 config — best measured): block = (b, chunk of 64
// rows), 512 threads = 8 waves, 8 rows/wave in sub-batches of 4. Contiguous-
// pass layout: pass i, lane l covers dims i*256 + l*4 (every load = contiguous
// 1KB); head = 4i + (l>>4). 1024 blocks = 4 blocks/CU. PLAIN launch_bounds:
// a (512,8) bound clamps VGPR to 32 and spills (round-6 lesson). Pushing to
// 8 blocks/CU (round 9) gave no gain: ~4.2 TB/s nt-read is the plateau.
// ---------------------------------------------------------------------------
__global__ __launch_bounds__(512) void attn_part(
    const float* __restrict__ qkv,       // [32][3072]
    const float* __restrict__ k_cache,   // [32][2048][1024]
    const float* __restrict__ v_cache,
    float* __restrict__ pacc,            // [32][32][1024]
    float* __restrict__ pm,              // [32][32][16]
    float* __restrict__ pl)              // [32][32][16]
{
    const int b = (int)(blockIdx.x >> 5);
    const int c = (int)(blockIdx.x & 31);
    const int tid = (int)threadIdx.x;
    const int w = tid >> 6;      // wave 0..7
    const int l = tid & 63;

    const float* qrow = qkv + (size_t)b * 3072 + l * 4;
    float4 q[4];
#pragma unroll
    for (int i = 0; i < 4; ++i) q[i] = *(const float4*)(qrow + i * 256);

    const size_t rowbase = ((size_t)b * KVLEN + c * ROWS_PER_BLOCK + w * ROWS_PER_WAVE) * HDIM + l * 4;
    const float* kb = k_cache + rowbase;
    const float* vb = v_cache + rowbase;

    float m[4], ls[4];
    float4 acc[4];
#pragma unroll
    for (int i = 0; i < 4; ++i) {
        m[i] = -1e30f; ls[i] = 0.f;
        acc[i] = make_float4(0.f, 0.f, 0.f, 0.f);
    }

#pragma unroll
    for (int sb = 0; sb < 2; ++sb) {
        float4 kf[4][4];
#pragma unroll
        for (int r = 0; r < 4; ++r)
#pragma unroll
            for (int i = 0; i < 4; ++i)
                kf[r][i] = ntload4(kb + (size_t)(sb * 4 + r) * HDIM + i * 256);
        float s[4][4];
#pragma unroll
        for (int r = 0; r < 4; ++r) {
#pragma unroll
            for (int i = 0; i < 4; ++i) {
                float d = kf[r][i].x * q[i].x + kf[r][i].y * q[i].y
                        + kf[r][i].z * q[i].z + kf[r][i].w * q[i].w;
                d += __shfl_xor(d, 1, 64);
                d += __shfl_xor(d, 2, 64);
                d += __shfl_xor(d, 4, 64);
                d += __shfl_xor(d, 8, 64);
                s[r][i] = d * 0.125f;
            }
        }
        float4 vf[4][4];
#pragma unroll
        for (int r = 0; r < 4; ++r)
#pragma unroll
            for (int i = 0; i < 4; ++i)
                vf[r][i] = ntload4(vb + (size_t)(sb * 4 + r) * HDIM + i * 256);
#pragma unroll
        for (int i = 0; i < 4; ++i) {
            float mn = fmaxf(fmaxf(s[0][i], s[1][i]), fmaxf(s[2][i], s[3][i]));
            mn = fmaxf(mn, m[i]);
            const float corr = __expf(m[i] - mn);
            const float p0 = __expf(s[0][i] - mn);
            const float p1 = __expf(s[1][i] - mn);
            const float p2 = __expf(s[2][i] - mn);
            const float p3 = __expf(s[3][i] - mn);
            ls[i] = ls[i] * corr + (p0 + p1) + (p2 + p3);
            m[i] = mn;
            acc[i].x = acc[i].x * corr + p0 * vf[0][i].x + p1 * vf[1][i].x + p2 * vf[2][i].x + p3 * vf[3][i].x;
            acc[i].y = acc[i].y * corr + p0 * vf[0][i].y + p1 * vf[1][i].y + p2 * vf[2][i].y + p3 * vf[3][i].y;
            acc[i].z = acc[i].z * corr + p0 * vf[0][i].z + p1 * vf[1][i].z + p2 * vf[2][i].z + p3 * vf[3][i].z;
            acc[i].w = acc[i].w * corr + p0 * vf[0][i].w + p1 * vf[1][i].w + p2 * vf[2][i].w + p3 * vf[3][i].w;
        }
    }

    __shared__ float sacc[8][1024];
    __shared__ float smm[8][16], sll[8][16];
#pragma unroll
    for (int i = 0; i < 4; ++i)
        *(float4*)&sacc[w][i * 256 + l * 4] = acc[i];
    if ((l & 15) == 0) {
        const int g = l >> 4;
#pragma unroll
        for (int i = 0; i < 4; ++i) { smm[w][i * 4 + g] = m[i]; sll[w][i * 4 + g] = ls[i]; }
    }
    __syncthreads();

#pragma unroll
    for (int half = 0; half < 2; ++half) {
        const int p = tid + half * 512;
        const int h = p >> 6;
        float M = -1e30f;
#pragma unroll
        for (int w2 = 0; w2 < 8; ++w2) M = fmaxf(M, smm[w2][h]);
        float L = 0.f, o = 0.f;
#pragma unroll
        for (int w2 = 0; w2 < 8; ++w2) {
            const float f = __expf(smm[w2][h] - M);
            L += sll[w2][h] * f;
            o += sacc[w2][p] * f;
        }
        pacc[((size_t)b * NCHUNK + c) * 1024 + p] = o;
        if ((p & 63) == 0) {
            pm[((size_t)b * NCHUNK + c) * 16 + h] = M;
            pl[((size_t)b * NCHUNK + c) * 16 + h] = L;
        }
    }
}

// ---------------------------------------------------------------------------
// Attention pass 2: merge 32 chunk partials + appended token (row 2048).
// ---------------------------------------------------------------------------
__global__ __launch_bounds__(1024) void attn_finish(
    const float* __restrict__ qkv,
    const float* __restrict__ pacc, const float* __restrict__ pm,
    const float* __restrict__ pl, float* __restrict__ attn_out)
{
    const int b = (int)blockIdx.x;
    const int p = (int)threadIdx.x;
    const int h = p >> 6;
    const float qa = qkv[(size_t)b * 3072 + p];
    const float ka = qkv[(size_t)b * 3072 + 1024 + p];
    const float va = qkv[(size_t)b * 3072 + 2048 + p];
    float d = qa * ka;
#pragma unroll
    for (int off = 1; off < 64; off <<= 1) d += __shfl_xor(d, off, 64);
    const float s = d * 0.125f;

    float M = s;
#pragma unroll
    for (int c = 0; c < NCHUNK; ++c)
        M = fmaxf(M, pm[((size_t)b * NCHUNK + c) * 16 + h]);
    const float pa = __expf(s - M);
    float L = pa, o = pa * va;
#pragma unroll 8
    for (int c = 0; c < NCHUNK; ++c) {
        const float f = __expf(pm[((size_t)b * NCHUNK + c) * 16 + h] - M);
        L += pl[((size_t)b * NCHUNK + c) * 16 + h] * f;
        o += pacc[((size_t)b * NCHUNK + c) * 1024 + p] * f;
    }
    attn_out[(size_t)b * HDIM + p] = o / L;
}

// ---------------------------------------------------------------------------
// Row LayerNorm: 1 block per batch row of 1024.
// ---------------------------------------------------------------------------
__global__ __launch_bounds__(256) void ln_kernel(const float* __restrict__ in,
    const float* __restrict__ w, const float* __restrict__ bv,
    float* __restrict__ out)
{
    const int b = (int)blockIdx.x, tid = (int)threadIdx.x;
    const float4 v = ((const float4*)(in + (size_t)b * HDIM))[tid];
    float sum = v.x + v.y + v.z + v.w;
    float sq  = v.x * v.x + v.y * v.y + v.z * v.z + v.w * v.w;
#pragma unroll
    for (int off = 1; off < 64; off <<= 1) {
        sum += __shfl_xor(sum, off, 64);
        sq  += __shfl_xor(sq,  off, 64);
    }
    __shared__ float s1[4], s2[4];
    const int wid = tid >> 6, lane = tid & 63;
    if (lane == 0) { s1[wid] = sum; s2[wid] = sq; }
    __syncthreads();
    sum = s1[0] + s1[1] + s1[2] + s1[3];
    sq  = s2[0] + s2[1] + s2[2] + s2[3];
    const float mu = sum * (1.f / HDIM);
    const float var = sq * (1.f / HDIM) - mu * mu;
    const float rstd = rsqrtf(var + LN_EPS);
    const float4 wv = ((const float4*)w)[tid];
    const float4 bb = ((const float4*)bv)[tid];
    float4 o;
    o.x = (v.x - mu) * rstd * wv.x + bb.x;
    o.y = (v.y - mu) * rstd * wv.y + bb.y;
    o.z = (v.z - mu) * rstd * wv.z + bb.z;
    o.w = (v.w - mu) * rstd * wv.w + bb.w;
    ((float4*)(out + (size_t)b * HDIM))[tid] = o;
}

// ---------------------------------------------------------------------------
// MLP2 finish: sum 4 split-K partials + bias + residual, then LayerNorm.
// ---------------------------------------------------------------------------
__global__ __launch_bounds__(256) void mlp2_finish(const float* __restrict__ part,
    const float* __restrict__ x1, const float* __restrict__ mbias,
    const float* __restrict__ w, const float* __restrict__ bv,
    float* __restrict__ out)
{
    const int b = (int)blockIdx.x, tid = (int)threadIdx.x;
    float4 v = make_float4(0.f, 0.f, 0.f, 0.f);
#pragma unroll
    for (int c = 0; c < 4; ++c) {
        const float4 p = ((const float4*)(part + (size_t)c * 32768 + (size_t)b * HDIM))[tid];
        v.x += p.x; v.y += p.y; v.z += p.z; v.w += p.w;
    }
    const float4 r  = ((const float4*)(x1 + (size_t)b * HDIM))[tid];
    const float4 mb = ((const float4*)mbias)[tid];
    v.x += r.x + mb.x; v.y += r.y + mb.y; v.z += r.z + mb.z; v.w += r.w + mb.w;

    float sum = v.x + v.y + v.z + v.w;
    float sq  = v.x * v.x + v.y * v.y + v.z * v.z + v.w * v.w;
#pragma unroll
    for (int off = 1; off < 64; off <<= 1) {
        sum += __shfl_xor(sum, off, 64);
        sq  += __shfl_xor(sq,  off, 64);
    }
    __shared__ float s1[4], s2[4];
    const int wid = tid >> 6, lane = tid & 63;
    if (lane == 0) { s1[wid] = sum; s2[wid] = sq; }
    __syncthreads();
    sum = s1[0] + s1[1] + s1[2] + s1[3];
    sq  = s2[0] + s2[1] + s2[2] + s2[3];
    const float mu = sum * (1.f / HDIM);
    const float var = sq * (1.f / HDIM) - mu * mu;
    const float rstd = rsqrtf(var + LN_EPS);
    const float4 wv = ((const float4*)w)[tid];
    const float4 bb = ((const float4*)bv)[tid];
    float4 o;
    o.x = (v.x - mu) * rstd * wv.x + bb.x;
    o.y = (v.y - mu) * rstd * wv.y + bb.y;
    o.z = (v.z - mu) * rstd * wv.z + bb.z;
    o.w = (v.w - mu) * rstd * wv.w + bb.w;
    ((float4*)(out + (size_t)b * HDIM))[tid] = o;
}

extern "C" void kernel_launch(void* const* d_in, const int* in_sizes, int n_in,
                              void* d_out, int out_size, void* d_ws, size_t ws_size,
                              hipStream_t stream) {
    const float* x     = (const float*)d_in[0];
    const float* kc    = (const float*)d_in[1];
    const float* vc    = (const float*)d_in[2];
    const float* qkvw  = (const float*)d_in[3];
    const float* qkvb  = (const float*)d_in[4];
    const float* outw  = (const float*)d_in[5];
    const float* outb  = (const float*)d_in[6];
    const float* nw1   = (const float*)d_in[7];
    const float* nb1   = (const float*)d_in[8];
    const float* nw2   = (const float*)d_in[9];
    const float* nb2   = (const float*)d_in[10];
    const float* mw1   = (const float*)d_in[11];
    const float* mb1   = (const float*)d_in[12];
    const float* mw2   = (const float*)d_in[13];
    const float* mb2   = (const float*)d_in[14];
    float* out = (float*)d_out;

    float* ws   = (float*)d_ws;
    float* qkv  = ws;              // [32][3072]           = 98304
    float* pacc = ws + 98304;      // [32][32][1024]       = 1048576
    float* pmb  = ws + 1146880;    // [32][32][16]         = 16384
    float* plb  = ws + 1163264;    // [32][32][16]         = 16384
    float* attn = ws + 1179648;    // [32][1024]
    float* y1   = ws + 1212416;    // [32][1024]
    float* x1   = ws + 1245184;    // [32][1024]
    // pacc region is dead after attn_finish -> reuse for MLP buffers
    float* hbuf = pacc;            // [32][4096]           = 131072
    float* part = pacc + 131072;   // [4][32][1024]        = 131072

    // 1) fused QKV projection: ROWS=2 -> 1536 waves = 384 blocks
    gemv_k1024<2, false, true, false, true><<<dim3(384, 1), 256, 0, stream>>>(
        x, HDIM, 0, qkvw, HDIM, 0, qkvb, nullptr, 0, qkv, 3 * HDIM, 0, out, 3 * HDIM);

    // 2) attention pass 1: chunk partials (1024 blocks = 4/CU, nt streaming)
    attn_part<<<BATCH * NCHUNK, 512, 0, stream>>>(qkv, kc, vc, pacc, pmb, plb);

    // 3) attention pass 2: merge chunks + appended token
    attn_finish<<<BATCH, 1024, 0, stream>>>(qkv, pacc, pmb, plb, attn);

    // 4) output projection + residual: ROWS=1 -> 1024 waves = 256 blocks
    gemv_k1024<1, false, true, true, false><<<dim3(256, 1), 256, 0, stream>>>(
        attn, HDIM, 0, outw, HDIM, 0, outb, x, HDIM, y1, HDIM, 0, nullptr, HDIM);

    // 5) LayerNorm 1
    ln_kernel<<<BATCH, 256, 0, stream>>>(y1, nw1, nb1, x1);

    // 6) MLP up + ReLU: ROWS=2 -> 2048 waves = 512 blocks
    gemv_k1024<2, true, true, false, false><<<dim3(512, 1), 256, 0, stream>>>(
        x1, HDIM, 0, mw1, HDIM, 0, mb1, nullptr, 0, hbuf, FFDIM, 0, nullptr, FFDIM);

    // 7) MLP down: ROWS=1, split-K 4 -> (256, 4) = 1024 blocks
    gemv_k1024<1, false, false, false, false><<<dim3(256, 4), 256, 0, stream>>>(
        hbuf, FFDIM, HDIM, mw2, FFDIM, HDIM, nullptr, nullptr, 0,
        part, HDIM, BATCH * HDIM, nullptr, HDIM);

    // 8) reduce partials + bias + residual + LayerNorm 2 -> x output
    mlp2_finish<<<BATCH, 256, 0, stream>>>(part, x1, mb2, nw2, nb2, out);
}

// Round 12
// 163.980 us; speedup vs baseline: 1.1819x; 1.0222x over previous
//
#include <hip/hip_runtime.h>

#define BATCH 32
#define KVLEN 2048
#define HDIM 1024
#define NHEAD 16
#define DHEAD 64
#define FFDIM 4096
#define LN_EPS 1e-5f
#define NCHUNK 32
#define ROWS_PER_BLOCK 64    // 8 waves * 8 rows
#define ROWS_PER_WAVE 8

// Non-temporal float4 load (emits global_load_dwordx4 nt): evict-first,
// L2-bypass path. Round-12 experiment: K stream stays nt, V stream uses the
// regular cached path — if the two paths have separate throughput limiters
// sharing only HBM, the aggregate read rate should exceed either alone
// (nt-only = 4.2 TB/s, cached-only = 3.4 TB/s, writes = 7 TB/s).
typedef float f32x4_t __attribute__((ext_vector_type(4)));
__device__ __forceinline__ float4 ntload4(const float* p) {
    f32x4_t v = __builtin_nontemporal_load((const f32x4_t*)p);
    return make_float4(v.x, v.y, v.z, v.w);
}

// ---------------------------------------------------------------------------
// GEMV over K=1024 chunk: out[b][j] = act(dot + bias + res).
// ROWS j-rows per wave; weight fragments persist in registers (nt-loaded,
// streamed once). 8-batch unroll: eight independent reduce chains hide the
// ~240cy shuffle-chain latency (GEMVs are latency-bound, not BW-bound).
// ---------------------------------------------------------------------------
template<int ROWS, bool RELU, bool HAS_BIAS, bool HAS_RES, bool DUP_IKIV>
__global__ __launch_bounds__(256) void gemv_k1024(
    const float* __restrict__ in, int in_bstride, int in_coff,
    const float* __restrict__ W, int w_jstride, int w_coff,
    const float* __restrict__ bias,
    const float* __restrict__ res, int res_bstride,
    float* __restrict__ out, int out_bstride, int out_coff,
    float* __restrict__ out_extra,
    int nJ)
{
    const int wave = (int)((blockIdx.x * blockDim.x + threadIdx.x) >> 6);
    const int lane = (int)(threadIdx.x & 63);
    const int j0 = wave * ROWS;
    if (j0 >= nJ) return;
    const int c = (int)blockIdx.y;
    const float* inp = in + (size_t)c * in_coff;
    const float* Wp  = W  + (size_t)c * w_coff;
    float* outp      = out + (size_t)c * out_coff;

    float4 w[ROWS][4];
#pragma unroll
    for (int jj = 0; jj < ROWS; ++jj) {
        const float* wr = Wp + (size_t)(j0 + jj) * w_jstride;
#pragma unroll
        for (int i = 0; i < 4; ++i) w[jj][i] = ntload4(wr + (lane + i * 64) * 4);
    }

    for (int b = 0; b < BATCH; b += 8) {
        float4 xv[8][4];
#pragma unroll
        for (int u = 0; u < 8; ++u) {
            const float4* xr = (const float4*)(inp + (size_t)(b + u) * in_bstride);
#pragma unroll
            for (int i = 0; i < 4; ++i) xv[u][i] = xr[lane + i * 64];
        }
        float s[8][ROWS];
#pragma unroll
        for (int u = 0; u < 8; ++u)
#pragma unroll
            for (int jj = 0; jj < ROWS; ++jj) {
                float a = 0.f;
#pragma unroll
                for (int i = 0; i < 4; ++i)
                    a += w[jj][i].x * xv[u][i].x + w[jj][i].y * xv[u][i].y
                       + w[jj][i].z * xv[u][i].z + w[jj][i].w * xv[u][i].w;
                s[u][jj] = a;
            }
        float v[8];
#pragma unroll
        for (int u = 0; u < 8; ++u) {
            if (ROWS == 4) {
                const bool b0 = (lane & 1), b1 = (lane & 2);
                float a0 = b0 ? s[u][0] : s[u][1];
                float t0 = (b0 ? s[u][1] : s[u][0]) + __shfl_xor(a0, 1, 64);
                float a1 = b0 ? s[u][2] : s[u][3];
                float t1 = (b0 ? s[u][3] : s[u][2]) + __shfl_xor(a1, 1, 64);
                float a2 = b1 ? t0 : t1;
                float r  = (b1 ? t1 : t0) + __shfl_xor(a2, 2, 64);
                r += __shfl_xor(r, 4, 64);
                r += __shfl_xor(r, 8, 64);
                r += __shfl_xor(r, 16, 64);
                r += __shfl_xor(r, 32, 64);
                v[u] = r;
            } else if (ROWS == 2) {
                const bool b0 = (lane & 1);
                float a0 = b0 ? s[u][0] : s[u][1];
                float r  = (b0 ? s[u][1] : s[u][0]) + __shfl_xor(a0, 1, 64);
                r += __shfl_xor(r, 2, 64);
                r += __shfl_xor(r, 4, 64);
                r += __shfl_xor(r, 8, 64);
                r += __shfl_xor(r, 16, 64);
                r += __shfl_xor(r, 32, 64);
                v[u] = r;
            } else {  // ROWS == 1
                float r = s[u][0];
                r += __shfl_xor(r, 1, 64);
                r += __shfl_xor(r, 2, 64);
                r += __shfl_xor(r, 4, 64);
                r += __shfl_xor(r, 8, 64);
                r += __shfl_xor(r, 16, 64);
                r += __shfl_xor(r, 32, 64);
                v[u] = r;
            }
        }
#pragma unroll
        for (int u = 0; u < 8; ++u) {
            if (lane < ROWS) {
                const int j = j0 + lane;
                float o = v[u];
                if (HAS_BIAS) o += bias[j];
                if (HAS_RES)  o += res[(size_t)(b + u) * res_bstride + j];
                if (RELU)     o = fmaxf(o, 0.f);
                outp[(size_t)(b + u) * out_bstride + j] = o;
                if (DUP_IKIV && j >= 1024) {
                    const int base = (j >= 2048) ? 65536 : 32768;
                    out_extra[base + (b + u) * 1024 + (j & 1023)] = o;
                }
            }
        }
    }
}

// ---------------------------------------------------------------------------
// Attention pass 1 (round-8 config, K=nt / V=cached split): block = (b, chunk
// of 64 rows), 512 threads = 8 waves, 8 rows/wave in sub-batches of 4.
// Contiguous-pass layout: pass i, lane l covers dims i*256 + l*4 (every load
// = contiguous 1KB); head = 4i + (l>>4). 1024 blocks = 4 blocks/CU.
// ---------------------------------------------------------------------------
__global__ __launch_bounds__(512) void attn_part(
    const float* __restrict__ qkv,       // [32][3072]
    const float* __restrict__ k_cache,   // [32][2048][1024]
    const float* __restrict__ v_cache,
    float* __restrict__ pacc,            // [32][32][1024]
    float* __restrict__ pm,              // [32][32][16]
    float* __restrict__ pl)              // [32][32][16]
{
    const int b = (int)(blockIdx.x >> 5);
    const int c = (int)(blockIdx.x & 31);
    const int tid = (int)threadIdx.x;
    const int w = tid >> 6;      // wave 0..7
    const int l = tid & 63;

    const float* qrow = qkv + (size_t)b * 3072 + l * 4;
    float4 q[4];
#pragma unroll
    for (int i = 0; i < 4; ++i) q[i] = *(const float4*)(qrow + i * 256);

    const size_t rowbase = ((size_t)b * KVLEN + c * ROWS_PER_BLOCK + w * ROWS_PER_WAVE) * HDIM + l * 4;
    const float* kb = k_cache + rowbase;
    const float* vb = v_cache + rowbase;

    float m[4], ls[4];
    float4 acc[4];
#pragma unroll
    for (int i = 0; i < 4; ++i) {
        m[i] = -1e30f; ls[i] = 0.f;
        acc[i] = make_float4(0.f, 0.f, 0.f, 0.f);
    }

#pragma unroll
    for (int sb = 0; sb < 2; ++sb) {
        // --- K loads: nt (L2-bypass path) ---
        float4 kf[4][4];
#pragma unroll
        for (int r = 0; r < 4; ++r)
#pragma unroll
            for (int i = 0; i < 4; ++i)
                kf[r][i] = ntload4(kb + (size_t)(sb * 4 + r) * HDIM + i * 256);
        float s[4][4];
#pragma unroll
        for (int r = 0; r < 4; ++r) {
#pragma unroll
            for (int i = 0; i < 4; ++i) {
                float d = kf[r][i].x * q[i].x + kf[r][i].y * q[i].y
                        + kf[r][i].z * q[i].z + kf[r][i].w * q[i].w;
                d += __shfl_xor(d, 1, 64);
                d += __shfl_xor(d, 2, 64);
                d += __shfl_xor(d, 4, 64);
                d += __shfl_xor(d, 8, 64);
                s[r][i] = d * 0.125f;
            }
        }
        // --- V loads: regular cached path (separate limiter experiment) ---
        float4 vf[4][4];
#pragma unroll
        for (int r = 0; r < 4; ++r)
#pragma unroll
            for (int i = 0; i < 4; ++i)
                vf[r][i] = *(const float4*)(vb + (size_t)(sb * 4 + r) * HDIM + i * 256);
#pragma unroll
        for (int i = 0; i < 4; ++i) {
            float mn = fmaxf(fmaxf(s[0][i], s[1][i]), fmaxf(s[2][i], s[3][i]));
            mn = fmaxf(mn, m[i]);
            const float corr = __expf(m[i] - mn);
            const float p0 = __expf(s[0][i] - mn);
            const float p1 = __expf(s[1][i] - mn);
            const float p2 = __expf(s[2][i] - mn);
            const float p3 = __expf(s[3][i] - mn);
            ls[i] = ls[i] * corr + (p0 + p1) + (p2 + p3);
            m[i] = mn;
            acc[i].x = acc[i].x * corr + p0 * vf[0][i].x + p1 * vf[1][i].x + p2 * vf[2][i].x + p3 * vf[3][i].x;
            acc[i].y = acc[i].y * corr + p0 * vf[0][i].y + p1 * vf[1][i].y + p2 * vf[2][i].y + p3 * vf[3][i].y;
            acc[i].z = acc[i].z * corr + p0 * vf[0][i].z + p1 * vf[1][i].z + p2 * vf[2][i].z + p3 * vf[3][i].z;
            acc[i].w = acc[i].w * corr + p0 * vf[0][i].w + p1 * vf[1][i].w + p2 * vf[2][i].w + p3 * vf[3][i].w;
        }
    }

    __shared__ float sacc[8][1024];
    __shared__ float smm[8][16], sll[8][16];
#pragma unroll
    for (int i = 0; i < 4; ++i)
        *(float4*)&sacc[w][i * 256 + l * 4] = acc[i];
    if ((l & 15) == 0) {
        const int g = l >> 4;
#pragma unroll
        for (int i = 0; i < 4; ++i) { smm[w][i * 4 + g] = m[i]; sll[w][i * 4 + g] = ls[i]; }
    }
    __syncthreads();

#pragma unroll
    for (int half = 0; half < 2; ++half) {
        const int p = tid + half * 512;
        const int h = p >> 6;
        float M = -1e30f;
#pragma unroll
        for (int w2 = 0; w2 < 8; ++w2) M = fmaxf(M, smm[w2][h]);
        float L = 0.f, o = 0.f;
#pragma unroll
        for (int w2 = 0; w2 < 8; ++w2) {
            const float f = __expf(smm[w2][h] - M);
            L += sll[w2][h] * f;
            o += sacc[w2][p] * f;
        }
        pacc[((size_t)b * NCHUNK + c) * 1024 + p] = o;
        if ((p & 63) == 0) {
            pm[((size_t)b * NCHUNK + c) * 16 + h] = M;
            pl[((size_t)b * NCHUNK + c) * 16 + h] = L;
        }
    }
}

// ---------------------------------------------------------------------------
// Attention pass 2: merge 32 chunk partials + appended token (row 2048).
// ---------------------------------------------------------------------------
__global__ __launch_bounds__(1024) void attn_finish(
    const float* __restrict__ qkv,
    const float* __restrict__ pacc, const float* __restrict__ pm,
    const float* __restrict__ pl, float* __restrict__ attn_out)
{
    const int b = (int)blockIdx.x;
    const int p = (int)threadIdx.x;
    const int h = p >> 6;
    const float qa = qkv[(size_t)b * 3072 + p];
    const float ka = qkv[(size_t)b * 3072 + 1024 + p];
    const float va = qkv[(size_t)b * 3072 + 2048 + p];
    float d = qa * ka;
#pragma unroll
    for (int off = 1; off < 64; off <<= 1) d += __shfl_xor(d, off, 64);
    const float s = d * 0.125f;

    float M = s;
#pragma unroll
    for (int c = 0; c < NCHUNK; ++c)
        M = fmaxf(M, pm[((size_t)b * NCHUNK + c) * 16 + h]);
    const float pa = __expf(s - M);
    float L = pa, o = pa * va;
#pragma unroll 8
    for (int c = 0; c < NCHUNK; ++c) {
        const float f = __expf(pm[((size_t)b * NCHUNK + c) * 16 + h] - M);
        L += pl[((size_t)b * NCHUNK + c) * 16 + h] * f;
        o += pacc[((size_t)b * NCHUNK + c) * 1024 + p] * f;
    }
    attn_out[(size_t)b * HDIM + p] = o / L;
}

// ---------------------------------------------------------------------------
// Row LayerNorm: 1 block per batch row of 1024.
// ---------------------------------------------------------------------------
__global__ __launch_bounds__(256) void ln_kernel(const float* __restrict__ in,
    const float* __restrict__ w, const float* __restrict__ bv,
    float* __restrict__ out)
{
    const int b = (int)blockIdx.x, tid = (int)threadIdx.x;
    const float4 v = ((const float4*)(in + (size_t)b * HDIM))[tid];
    float sum = v.x + v.y + v.z + v.w;
    float sq  = v.x * v.x + v.y * v.y + v.z * v.z + v.w * v.w;
#pragma unroll
    for (int off = 1; off < 64; off <<= 1) {
        sum += __shfl_xor(sum, off, 64);
        sq  += __shfl_xor(sq,  off, 64);
    }
    __shared__ float s1[4], s2[4];
    const int wid = tid >> 6, lane = tid & 63;
    if (lane == 0) { s1[wid] = sum; s2[wid] = sq; }
    __syncthreads();
    sum = s1[0] + s1[1] + s1[2] + s1[3];
    sq  = s2[0] + s2[1] + s2[2] + s2[3];
    const float mu = sum * (1.f / HDIM);
    const float var = sq * (1.f / HDIM) - mu * mu;
    const float rstd = rsqrtf(var + LN_EPS);
    const float4 wv = ((const float4*)w)[tid];
    const float4 bb = ((const float4*)bv)[tid];
    float4 o;
    o.x = (v.x - mu) * rstd * wv.x + bb.x;
    o.y = (v.y - mu) * rstd * wv.y + bb.y;
    o.z = (v.z - mu) * rstd * wv.z + bb.z;
    o.w = (v.w - mu) * rstd * wv.w + bb.w;
    ((float4*)(out + (size_t)b * HDIM))[tid] = o;
}

// ---------------------------------------------------------------------------
// MLP2 finish: sum 4 split-K partials + bias + residual, then LayerNorm.
// ---------------------------------------------------------------------------
__global__ __launch_bounds__(256) void mlp2_finish(const float* __restrict__ part,
    const float* __restrict__ x1, const float* __restrict__ mbias,
    const float* __restrict__ w, const float* __restrict__ bv,
    float* __restrict__ out)
{
    const int b = (int)blockIdx.x, tid = (int)threadIdx.x;
    float4 v = make_float4(0.f, 0.f, 0.f, 0.f);
#pragma unroll
    for (int c = 0; c < 4; ++c) {
        const float4 p = ((const float4*)(part + (size_t)c * 32768 + (size_t)b * HDIM))[tid];
        v.x += p.x; v.y += p.y; v.z += p.z; v.w += p.w;
    }
    const float4 r  = ((const float4*)(x1 + (size_t)b * HDIM))[tid];
    const float4 mb = ((const float4*)mbias)[tid];
    v.x += r.x + mb.x; v.y += r.y + mb.y; v.z += r.z + mb.z; v.w += r.w + mb.w;

    float sum = v.x + v.y + v.z + v.w;
    float sq  = v.x * v.x + v.y * v.y + v.z * v.z + v.w * v.w;
#pragma unroll
    for (int off = 1; off < 64; off <<= 1) {
        sum += __shfl_xor(sum, off, 64);
        sq  += __shfl_xor(sq,  off, 64);
    }
    __shared__ float s1[4], s2[4];
    const int wid = tid >> 6, lane = tid & 63;
    if (lane == 0) { s1[wid] = sum; s2[wid] = sq; }
    __syncthreads();
    sum = s1[0] + s1[1] + s1[2] + s1[3];
    sq  = s2[0] + s2[1] + s2[2] + s2[3];
    const float mu = sum * (1.f / HDIM);
    const float var = sq * (1.f / HDIM) - mu * mu;
    const float rstd = rsqrtf(var + LN_EPS);
    const float4 wv = ((const float4*)w)[tid];
    const float4 bb = ((const float4*)bv)[tid];
    float4 o;
    o.x = (v.x - mu) * rstd * wv.x + bb.x;
    o.y = (v.y - mu) * rstd * wv.y + bb.y;
    o.z = (v.z - mu) * rstd * wv.z + bb.z;
    o.w = (v.w - mu) * rstd * wv.w + bb.w;
    ((float4*)(out + (size_t)b * HDIM))[tid] = o;
}

extern "C" void kernel_launch(void* const* d_in, const int* in_sizes, int n_in,
                              void* d_out, int out_size, void* d_ws, size_t ws_size,
                              hipStream_t stream) {
    const float* x     = (const float*)d_in[0];
    const float* kc    = (const float*)d_in[1];
    const float* vc    = (const float*)d_in[2];
    const float* qkvw  = (const float*)d_in[3];
    const float* qkvb  = (const float*)d_in[4];
    const float* outw  = (const float*)d_in[5];
    const float* outb  = (const float*)d_in[6];
    const float* nw1   = (const float*)d_in[7];
    const float* nb1   = (const float*)d_in[8];
    const float* nw2   = (const float*)d_in[9];
    const float* nb2   = (const float*)d_in[10];
    const float* mw1   = (const float*)d_in[11];
    const float* mb1   = (const float*)d_in[12];
    const float* mw2   = (const float*)d_in[13];
    const float* mb2   = (const float*)d_in[14];
    float* out = (float*)d_out;

    float* ws   = (float*)d_ws;
    float* qkv  = ws;              // [32][3072]           = 98304
    float* pacc = ws + 98304;      // [32][32][1024]       = 1048576
    float* pmb  = ws + 1146880;    // [32][32][16]         = 16384
    float* plb  = ws + 1163264;    // [32][32][16]         = 16384
    float* attn = ws + 1179648;    // [32][1024]
    float* y1   = ws + 1212416;    // [32][1024]
    float* x1   = ws + 1245184;    // [32][1024]
    // pacc region is dead after attn_finish -> reuse for MLP buffers
    float* hbuf = pacc;            // [32][4096]           = 131072
    float* part = pacc + 131072;   // [4][32][1024]        = 131072

    // 1) fused QKV projection: ROWS=2 -> 1536 waves = 384 blocks
    gemv_k1024<2, false, true, false, true><<<dim3(384, 1), 256, 0, stream>>>(
        x, HDIM, 0, qkvw, HDIM, 0, qkvb, nullptr, 0, qkv, 3 * HDIM, 0, out, 3 * HDIM);

    // 2) attention pass 1: chunk partials (1024 blocks = 4/CU, K=nt V=cached)
    attn_part<<<BATCH * NCHUNK, 512, 0, stream>>>(qkv, kc, vc, pacc, pmb, plb);

    // 3) attention pass 2: merge chunks + appended token
    attn_finish<<<BATCH, 1024, 0, stream>>>(qkv, pacc, pmb, plb, attn);

    // 4) output projection + residual: ROWS=1 -> 1024 waves = 256 blocks
    gemv_k1024<1, false, true, true, false><<<dim3(256, 1), 256, 0, stream>>>(
        attn, HDIM, 0, outw, HDIM, 0, outb, x, HDIM, y1, HDIM, 0, nullptr, HDIM);

    // 5) LayerNorm 1
    ln_kernel<<<BATCH, 256, 0, stream>>>(y1, nw1, nb1, x1);

    // 6) MLP up + ReLU: ROWS=2 -> 2048 waves = 512 blocks
    gemv_k1024<2, true, true, false, false><<<dim3(512, 1), 256, 0, stream>>>(
        x1, HDIM, 0, mw1, HDIM, 0, mb1, nullptr, 0, hbuf, FFDIM, 0, nullptr, FFDIM);

    // 7) MLP down: ROWS=1, split-K 4 -> (256, 4) = 1024 blocks
    gemv_k1024<1, false, false, false, false><<<dim3(256, 4), 256, 0, stream>>>(
        hbuf, FFDIM, HDIM, mw2, FFDIM, HDIM, nullptr, nullptr, 0,
        part, HDIM, BATCH * HDIM, nullptr, HDIM);

    // 8) reduce partials + bias + residual + LayerNorm 2 -> x output
    mlp2_finish<<<BATCH, 256, 0, stream>>>(part, x1, mb2, nw2, nb2, out);
}